// Round 5
// baseline (256.325 us; speedup 1.0000x reference)
//
#include <hip/hip_runtime.h>
#include <math.h>

// ---------------------------------------------------------------------------
// RWKV7-ish CausalSelfAttention, MI355X gfx950.
// B=4 T=2048 C=1024 NH=16 HS=64.
// Pipeline: fused cast(x,Wa,Wp)->bf16 ;
//   GEMM1(256x128 block, 128x64 wave tiles, BK=64, A via GLL16 DMA +
//         swizzled LDS, B fragments DIRECT FROM L2 into registers)
//         + fused groupnorm/fast-erf -> E ;
//   band_vt rolling chunked scan -> vt ;
//   GEMM2(128x128 block, same B-from-L2 scheme, 3 blocks/CU) + residual.
// R5 rationale: gemm1 was LDS-port-bound (reads 96KB + writes 48KB per
//   K-tile vs 1032cyc MFMA). B is weights; grid x=24 (=0 mod 8) makes all
//   same-B-panel blocks land on one XCD -> B panels are L2-resident
//   (768KB/XCD). Reading B frags straight from L2 cuts LDS traffic 34%
//   and staging DMA 12->8, with NO new waits: the b128 reg-loads are
//   issued with the A staging and covered by the existing syncthreads
//   vmcnt(0) drain. K-order identical -> bit-identical numerics.
// Workspace: xb 16MB | Wab 6MB | Wpb 2MB | E 48MB | vt 16MB = 88MiB
// ---------------------------------------------------------------------------

typedef __attribute__((ext_vector_type(8))) short short8;     // 8 x bf16 bits
typedef __attribute__((ext_vector_type(4))) float floatx4;

#define GLL16(g, l)                                                            \
    __builtin_amdgcn_global_load_lds(                                          \
        (const __attribute__((address_space(1))) void*)(g),                    \
        (__attribute__((address_space(3))) void*)(l), 16, 0, 0)

static __device__ __forceinline__ unsigned short f2bf(float f) {
    unsigned u = __float_as_uint(f);
    unsigned r = (u + 0x7fffu + ((u >> 16) & 1u)) >> 16;
    return (unsigned short)r;
}
static __device__ __forceinline__ float bflo(unsigned v) { return __uint_as_float(v << 16); }

// Abramowitz-Stegun 7.1.28: |err| <= 3e-7, branch-free.
static __device__ __forceinline__ float erf_fast(float x) {
    float ax = __builtin_fabsf(x);
    float p = fmaf(0.0000430638f, ax, 0.0002765672f);
    p = fmaf(p, ax, 0.0001520143f);
    p = fmaf(p, ax, 0.0092705272f);
    p = fmaf(p, ax, 0.0422820123f);
    p = fmaf(p, ax, 0.0705230784f);
    p = fmaf(p, ax, 1.0f);
    float r = 1.0f / p;
    float r2 = r * r, r4 = r2 * r2, r8 = r4 * r4, r16 = r8 * r8;
    return __builtin_copysignf(1.0f - r16, x);
}

// sum across the 16 lanes of a DPP row, result in every lane of the row.
static __device__ __forceinline__ float sum16(float x) {
    int t;
    t = __builtin_amdgcn_update_dpp(0, __float_as_int(x), 0x128, 0xf, 0xf, false); // row_ror:8
    x += __int_as_float(t);
    t = __builtin_amdgcn_update_dpp(0, __float_as_int(x), 0x124, 0xf, 0xf, false); // row_ror:4
    x += __int_as_float(t);
    t = __builtin_amdgcn_update_dpp(0, __float_as_int(x), 0x122, 0xf, 0xf, false); // row_ror:2
    x += __int_as_float(t);
    t = __builtin_amdgcn_update_dpp(0, __float_as_int(x), 0x121, 0xf, 0xf, false); // row_ror:1
    x += __int_as_float(t);
    return x;
}
// full 64-lane sum, result in every lane.
static __device__ __forceinline__ float sum64_all(float x) {
    x = sum16(x);
    int t = __builtin_amdgcn_ds_swizzle(__float_as_int(x), 0x401F);  // xor 16 (within 32)
    x += __int_as_float(t);
    x += __shfl_xor(x, 32, 64);                                      // xor 32
    return x;
}

// ---------------- fused cast fp32 -> bf16 (x | Wa | Wp, contiguous out) -----
__global__ __launch_bounds__(256) void castall(const float4* __restrict__ x,
                                               const float4* __restrict__ wa,
                                               const float4* __restrict__ wp,
                                               uint2* __restrict__ out) {
    int i = blockIdx.x * 256 + threadIdx.x;      // boundaries are block-aligned
    const float4* src;
    int off;
    if (i < 2097152)      { src = x;  off = 0; }
    else if (i < 2883584) { src = wa; off = 2097152; }
    else                  { src = wp; off = 2883584; }
    float4 v = src[i - off];
    uint2 o;
    o.x = (unsigned)f2bf(v.x) | ((unsigned)f2bf(v.y) << 16);
    o.y = (unsigned)f2bf(v.z) | ((unsigned)f2bf(v.w) << 16);
    out[i] = o;
}

// ---------------- GEMM1: qkv = xb @ Wab^T, fused norm+erf -> E --------------
// Block tile 256x128, 4 waves 2x2, wave tile 128x64 (acc[8][4]). BK=64.
// A: GLL16 DMA -> swizzled LDS (slot (c+r)&7, conflict-free, as R1-proven).
// B: 8x global_load b128 per lane per K-tile, straight to registers.
//    col = half*32 + quad*8 matches exactly what the old LDS swizzle read
//    (chunk (swb - fb)&7 = quad / quad+4) -> identical K order & numerics.
// E layout: [three][b][h][t][hs], bf16 bits.
__global__ __launch_bounds__(256, 2) void gemm1_qkv_norm(const unsigned short* __restrict__ A,
                                                         const unsigned short* __restrict__ Bm,
                                                         unsigned short* __restrict__ E) {
    __shared__ unsigned short As[256 * 64];   // 32 KB
    const int tid = threadIdx.x;
    const int lane = tid & 63, wav = tid >> 6;
    const int r16 = lane & 15, quad = lane >> 4;
    const int M0 = blockIdx.y * 256, N0 = blockIdx.x * 128;
    const int wm = wav >> 1, wn = wav & 1;
    const int m0 = M0 + wm * 128, n0 = N0 + wn * 64;
    const int rr0 = tid >> 3;
    const int cc0 = (tid - rr0) & 7;
    const unsigned short* pA0 = A + (size_t)(M0 + rr0) * 1024 + cc0 * 8;
    unsigned short* lA0 = As + (size_t)(wav * 64) * 8;
    const int fa = wm * 128 + r16;
    const int swa0 = (quad + fa) & 7, swa1 = (swa0 + 4) & 7;
    // B fragment base: row = N0 + wn*64 + j*16 + r16, col chunk = quad*8
    const unsigned short* pBg = Bm + (size_t)(N0 + wn * 64 + r16) * 1024 + quad * 8;

    floatx4 acc[8][4];
    #pragma unroll
    for (int i = 0; i < 8; i++)
        #pragma unroll
        for (int j = 0; j < 4; j++) acc[i][j] = (floatx4)0.0f;

    short8 bcur[2][4];
    #pragma unroll 1
    for (int ks = 0; ks < 16; ks++) {
        #pragma unroll
        for (int p = 0; p < 8; p++)
            GLL16(pA0 + (size_t)ks * 64 + (size_t)p * 32 * 1024, lA0 + (size_t)p * 2048);
        #pragma unroll
        for (int h = 0; h < 2; h++)
            #pragma unroll
            for (int j = 0; j < 4; j++)
                bcur[h][j] = *(const short8*)(pBg + (size_t)j * 16384 + ks * 64 + h * 32);
        __syncthreads();          // vmcnt(0) drain covers GLL16 AND bcur loads
        short8 af[8];
        #pragma unroll
        for (int i = 0; i < 8; i++)
            af[i] = *(const short8*)(As + (fa + i * 16) * 64 + swa0 * 8);
        #pragma unroll
        for (int i = 0; i < 8; i++)
            #pragma unroll
            for (int j = 0; j < 4; j++)
                acc[i][j] = __builtin_amdgcn_mfma_f32_16x16x32_bf16(
                    af[i], bcur[0][j], acc[i][j], 0, 0, 0);
        #pragma unroll
        for (int i = 0; i < 8; i++)
            af[i] = *(const short8*)(As + (fa + i * 16) * 64 + swa1 * 8);
        #pragma unroll
        for (int i = 0; i < 8; i++)
            #pragma unroll
            for (int j = 0; j < 4; j++)
                acc[i][j] = __builtin_amdgcn_mfma_f32_16x16x32_bf16(
                    af[i], bcur[1][j], acc[i][j], 0, 0, 0);
        __syncthreads();
    }

    // fused per-64-group normalization: this wave's 64-col tile == one (three,h)
    int gcol  = n0 >> 6;            // 0..47
    int three = gcol >> 4, h = gcol & 15;
    #pragma unroll
    for (int i = 0; i < 8; i++) {
        #pragma unroll
        for (int r = 0; r < 4; r++) {
            float s = 0.f, ss = 0.f;
            #pragma unroll
            for (int j = 0; j < 4; j++) { float v = acc[i][j][r]; s += v; ss += v * v; }
            s = sum16(s); ss = sum16(ss);
            float mean = s * (1.0f / 64.0f);
            float var  = (ss - s * s * (1.0f / 64.0f)) * (1.0f / 63.0f);  // ddof=1
            float rstd = rsqrtf(var);
            int rowm = m0 + i * 16 + quad * 4 + r;     // = b*2048 + t
            int bb = rowm >> 11, tt2 = rowm & 2047;
            size_t base = ((((size_t)three * 4 + bb) * 16 + h) * 2048 + tt2) * 64;
            #pragma unroll
            for (int j = 0; j < 4; j++) {
                float v = (acc[i][j][r] - mean) * rstd;
                if (three < 2) v = erf_fast(v);
                E[base + j * 16 + r16] = f2bf(v);
            }
        }
    }
}

// ---------------- GEMM2: out = x + vt @ Wp^T (fp32 out) ---------------------
// 128x128 block tile, 4 waves 2x2, wave tile 64x64 (acc[4][4]). BK=64.
// A via GLL16+LDS (16KB only); B frags direct from L2 (Wpb = 2MB, resident).
// 3 blocks/CU (LDS 16KB, launch_bounds(256,3)); grid (8,64) = 512 blocks.
__global__ __launch_bounds__(256, 3) void gemm2_proj_add(const unsigned short* __restrict__ A,
                                                         const unsigned short* __restrict__ Bm,
                                                         const float* __restrict__ X,
                                                         float* __restrict__ Out) {
    __shared__ unsigned short As[128 * 64];   // 16 KB
    const int tid = threadIdx.x;
    const int lane = tid & 63, wav = tid >> 6;
    const int r16 = lane & 15, quad = lane >> 4;
    const int M0 = blockIdx.y * 128, N0 = blockIdx.x * 128;
    const int wm = wav >> 1, wn = wav & 1;
    const int m0 = M0 + wm * 64, n0 = N0 + wn * 64;
    const int rr0 = tid >> 3;                      // 0..31
    const int cc0 = (tid - rr0) & 7;
    const unsigned short* pA0 = A + (size_t)(M0 + rr0) * 1024 + cc0 * 8;
    unsigned short* lA0 = As + (size_t)(wav * 64) * 8;
    const int fa = wm * 64 + r16;
    const int swa0 = (quad + fa) & 7, swa1 = (swa0 + 4) & 7;
    const unsigned short* pBg = Bm + (size_t)(N0 + wn * 64 + r16) * 1024 + quad * 8;

    floatx4 acc[4][4];
    #pragma unroll
    for (int i = 0; i < 4; i++)
        #pragma unroll
        for (int j = 0; j < 4; j++) acc[i][j] = (floatx4)0.0f;

    short8 bcur[2][4];
    #pragma unroll 1
    for (int ks = 0; ks < 16; ks++) {
        #pragma unroll
        for (int p = 0; p < 4; p++)
            GLL16(pA0 + (size_t)ks * 64 + (size_t)p * 32 * 1024, lA0 + (size_t)p * 2048);
        #pragma unroll
        for (int h = 0; h < 2; h++)
            #pragma unroll
            for (int j = 0; j < 4; j++)
                bcur[h][j] = *(const short8*)(pBg + (size_t)j * 16384 + ks * 64 + h * 32);
        __syncthreads();
        short8 af[4];
        #pragma unroll
        for (int i = 0; i < 4; i++)
            af[i] = *(const short8*)(As + (fa + i * 16) * 64 + swa0 * 8);
        #pragma unroll
        for (int i = 0; i < 4; i++)
            #pragma unroll
            for (int j = 0; j < 4; j++)
                acc[i][j] = __builtin_amdgcn_mfma_f32_16x16x32_bf16(
                    af[i], bcur[0][j], acc[i][j], 0, 0, 0);
        #pragma unroll
        for (int i = 0; i < 4; i++)
            af[i] = *(const short8*)(As + (fa + i * 16) * 64 + swa1 * 8);
        #pragma unroll
        for (int i = 0; i < 4; i++)
            #pragma unroll
            for (int j = 0; j < 4; j++)
                acc[i][j] = __builtin_amdgcn_mfma_f32_16x16x32_bf16(
                    af[i], bcur[1][j], acc[i][j], 0, 0, 0);
        __syncthreads();
    }

    #pragma unroll
    for (int i = 0; i < 4; i++)
        #pragma unroll
        for (int j = 0; j < 4; j++)
            #pragma unroll
            for (int r = 0; r < 4; r++) {
                size_t idx = (size_t)(m0 + i * 16 + quad * 4 + r) * 1024 + (n0 + j * 16 + r16);
                Out[idx] = acc[i][j][r] + X[idx];
            }
}

// ---------------- rolling chunked scan -> vt --------------------------------
// Exact recursion carried in registers: sv_t = v_t - G_t * sv_{t-1},
//   G_t = k~_{t-1}.k_t ; vt_t[i] = H0 sv_t[i] + w_i H1 sv_{t-1}[i].
// One wave per (b,h,chunk-of-16): 64 x 128 = 8192 waves = 2048 blocks.
__global__ __launch_bounds__(256) void band_vt(const unsigned short* __restrict__ E,
                                               const float* __restrict__ w,
                                               const float* __restrict__ eta,
                                               unsigned short* __restrict__ vt) {
    const int lane = threadIdx.x & 63;
    const int wav  = threadIdx.x >> 6;
    const int gid  = blockIdx.x * 4 + wav;        // 0..8191
    const int chunk = gid & 127;                  // 128 chunks of 16 t
    const int p     = gid >> 7;                   // (b,h): 0..63
    const int b = p >> 4, h = p & 15;
    const int t0 = chunk * 16;

    const size_t PL = (size_t)4 * 16 * 2048 * 64;               // one "three" plane
    const size_t pbh = ((size_t)b * 16 + h) * (2048 * 64);
    const unsigned short* qb = E + pbh;
    const unsigned short* kb = E + PL + pbh;
    const unsigned short* vb = E + 2 * PL + pbh;

    const float e  = eta[h * 64 + lane];
    const float wi = w[h * 64 + lane];

    // ---- warm-up: rolling kh_{t0-1} and seeded sv_{t0-1} (wave-uniform guards)
    float kh_p, sv_p;
    if (t0 == 0) {
        kh_p = 0.f;
        sv_p = 0.f;
    } else {
        float k1 = bflo(kb[(size_t)(t0 - 1) * 64 + lane]);
        float k2 = bflo(kb[(size_t)(t0 - 2) * 64 + lane]);
        float k3 = bflo(kb[(size_t)(t0 - 3) * 64 + lane]);
        float v1 = bflo(vb[(size_t)(t0 - 1) * 64 + lane]);
        float v2 = bflo(vb[(size_t)(t0 - 2) * 64 + lane]);
        float v3 = bflo(vb[(size_t)(t0 - 3) * 64 + lane]);
        float G1 = sum64_all((k2 * e) * k1);      // G_{t0-1} = k~_{t0-2}.k_{t0-1}
        float G2 = sum64_all((k3 * e) * k2);      // G_{t0-2} = k~_{t0-3}.k_{t0-2}
        sv_p = v1 - G1 * (v2 - G2 * v3);          // sv_{t0-1}, 3-term seed
        kh_p = k1 * e;
    }

    const unsigned short* pq = qb + (size_t)t0 * 64 + lane;
    const unsigned short* pk = kb + (size_t)t0 * 64 + lane;
    const unsigned short* pv = vb + (size_t)t0 * 64 + lane;
    unsigned short* po = vt + ((size_t)b * 2048 + t0) * 1024 + h * 64 + lane;

    #pragma unroll
    for (int tt = 0; tt < 16; tt++) {
        float qt = bflo(pq[tt * 64]);
        float kt = bflo(pk[tt * 64]);
        float vv = bflo(pv[tt * 64]);
        float kh = kt * e;
        float Gt = sum64_all(kh_p * kt);          // k~_{t-1}.k_t
        float H0 = sum64_all(kh * qt);            // k~_t.q_t
        float H1 = sum64_all(kh_p * qt);          // k~_{t-1}.q_t
        float sv = fmaf(-Gt, sv_p, vv);           // sv_t = v_t - G_t sv_{t-1}
        float r  = fmaf(H0, sv, wi * (H1 * sv_p));
        po[(size_t)tt * 1024] = f2bf(r);
        kh_p = kh;
        sv_p = sv;
    }
}

// ---------------------------------------------------------------------------
extern "C" void kernel_launch(void* const* d_in, const int* in_sizes, int n_in,
                              void* d_out, int out_size, void* d_ws, size_t ws_size,
                              hipStream_t stream) {
    const float* x   = (const float*)d_in[0];   // (4,2048,1024)
    const float* Wa  = (const float*)d_in[1];   // (3072,1024)
    const float* Wp  = (const float*)d_in[2];   // (1024,1024)
    const float* w   = (const float*)d_in[3];   // (1024,)
    const float* eta = (const float*)d_in[4];   // (1024,)
    float* out = (float*)d_out;

    char* ws = (char*)d_ws;
    unsigned short* xb  = (unsigned short*)(ws + 0);          // 16777216 B
    unsigned short* Wab = (unsigned short*)(ws + 16777216);   //  6291456 B
    unsigned short* Wpb = (unsigned short*)(ws + 23068672);   //  2097152 B
    unsigned short* E   = (unsigned short*)(ws + 25165824);   // 50331648 B
    unsigned short* vtb = (unsigned short*)(ws + 75497728);   // 16777216 B  -> end 92274944

    castall<<<12288, 256, 0, stream>>>((const float4*)x, (const float4*)Wa,
                                       (const float4*)Wp, (uint2*)xb);

    gemm1_qkv_norm<<<dim3(24, 32), 256, 0, stream>>>(xb, Wab, E);
    band_vt<<<2048, 256, 0, stream>>>(E, w, eta, vtb);
    gemm2_proj_add<<<dim3(8, 64), 256, 0, stream>>>(vtb, Wpb, x, out);
}

// Round 6
// 197.521 us; speedup vs baseline: 1.2977x; 1.2977x over previous
//
#include <hip/hip_runtime.h>
#include <math.h>

// ---------------------------------------------------------------------------
// RWKV7-ish CausalSelfAttention, MI355X gfx950.
// B=4 T=2048 C=1024 NH=16 HS=64.
// Pipeline: castall v2 (ILP-4 grid-stride) ->bf16 ;
//   GEMM1(256x128 block, 128x64 wave tiles, BK=64, GLL16 DMA + swizzled LDS,
//         XCD-bijective block swizzle) + fused groupnorm/fast-erf -> E ;
//   band_vt rolling chunked scan -> vt ;
//   GEMM2(128x128 block, 64x64 wave tiles, XCD swizzle) + residual.
// R5 lesson: per-lane B reg-loads from L2 inside the barrier window regress
//   badly (latency on critical path + VGPR pressure). Keep LDS-staged B.
// R6: XCD swizzle (T1) so blocks sharing an A-panel land on ONE XCD's L2:
//   gemm1 FETCH was 71MB vs 22MB ideal (A-panels refetched via L3/HBM).
//   swz = (wg&7)*(nwg/8) + (wg>>3); nwg = 768 / 512, both % 8 == 0 ->
//   bijective (ERRATA #11 satisfied).
// Workspace: xb 16MB | Wab 6MB | Wpb 2MB | E 48MB | vt 16MB = 88MiB
// ---------------------------------------------------------------------------

typedef __attribute__((ext_vector_type(8))) short short8;     // 8 x bf16 bits
typedef __attribute__((ext_vector_type(4))) float floatx4;

#define GLL16(g, l)                                                            \
    __builtin_amdgcn_global_load_lds(                                          \
        (const __attribute__((address_space(1))) void*)(g),                    \
        (__attribute__((address_space(3))) void*)(l), 16, 0, 0)

static __device__ __forceinline__ unsigned short f2bf(float f) {
    unsigned u = __float_as_uint(f);
    unsigned r = (u + 0x7fffu + ((u >> 16) & 1u)) >> 16;
    return (unsigned short)r;
}
static __device__ __forceinline__ float bflo(unsigned v) { return __uint_as_float(v << 16); }

// Abramowitz-Stegun 7.1.28: |err| <= 3e-7, branch-free.
static __device__ __forceinline__ float erf_fast(float x) {
    float ax = __builtin_fabsf(x);
    float p = fmaf(0.0000430638f, ax, 0.0002765672f);
    p = fmaf(p, ax, 0.0001520143f);
    p = fmaf(p, ax, 0.0092705272f);
    p = fmaf(p, ax, 0.0422820123f);
    p = fmaf(p, ax, 0.0705230784f);
    p = fmaf(p, ax, 1.0f);
    float r = 1.0f / p;
    float r2 = r * r, r4 = r2 * r2, r8 = r4 * r4, r16 = r8 * r8;
    return __builtin_copysignf(1.0f - r16, x);
}

// sum across the 16 lanes of a DPP row, result in every lane of the row.
static __device__ __forceinline__ float sum16(float x) {
    int t;
    t = __builtin_amdgcn_update_dpp(0, __float_as_int(x), 0x128, 0xf, 0xf, false); // row_ror:8
    x += __int_as_float(t);
    t = __builtin_amdgcn_update_dpp(0, __float_as_int(x), 0x124, 0xf, 0xf, false); // row_ror:4
    x += __int_as_float(t);
    t = __builtin_amdgcn_update_dpp(0, __float_as_int(x), 0x122, 0xf, 0xf, false); // row_ror:2
    x += __int_as_float(t);
    t = __builtin_amdgcn_update_dpp(0, __float_as_int(x), 0x121, 0xf, 0xf, false); // row_ror:1
    x += __int_as_float(t);
    return x;
}
// full 64-lane sum, result in every lane.
static __device__ __forceinline__ float sum64_all(float x) {
    x = sum16(x);
    int t = __builtin_amdgcn_ds_swizzle(__float_as_int(x), 0x401F);  // xor 16 (within 32)
    x += __int_as_float(t);
    x += __shfl_xor(x, 32, 64);                                      // xor 32
    return x;
}

// ---------------- fused cast fp32 -> bf16 (x | Wa | Wp, contiguous out) -----
// v2: 3072 blocks x 256 thr x 4 float4 each (chunk of 1024 per block, all
// region boundaries 1024-aligned -> branch stays block-uniform). ILP-4.
__global__ __launch_bounds__(256) void castall(const float4* __restrict__ x,
                                               const float4* __restrict__ wa,
                                               const float4* __restrict__ wp,
                                               uint2* __restrict__ out) {
    int base = blockIdx.x * 1024 + threadIdx.x;
    #pragma unroll
    for (int k = 0; k < 4; k++) {
        int i = base + k * 256;
        const float4* src;
        int off;
        if (i < 2097152)      { src = x;  off = 0; }
        else if (i < 2883584) { src = wa; off = 2097152; }
        else                  { src = wp; off = 2883584; }
        float4 v = src[i - off];
        uint2 o;
        o.x = (unsigned)f2bf(v.x) | ((unsigned)f2bf(v.y) << 16);
        o.y = (unsigned)f2bf(v.z) | ((unsigned)f2bf(v.w) << 16);
        out[i] = o;
    }
}

// ---------------------------------------------------------------------------
// GEMM core (proven R1/R4), C = A @ B^T (K contiguous in both operands).
// Block tile 256x128, 4 waves 2x2, wave tile 128x64 (acc[8][4]). BK=64.
// GLL16 DMA staging; LDS granule (row r, chunk c) at slot r*8 + ((c+r)&7)
//   -> staging and ds_read_b128 conflict-free (0 conflicts measured).
// M0_/N0_ passed in (XCD-swizzled by caller).
// ---------------------------------------------------------------------------
#define GEMM_CORE_BIG(A_, B_, Kc, M0_, N0_)                                    \
    __shared__ unsigned short As[256 * 64];   /* 32 KB */                      \
    __shared__ unsigned short Bs[128 * 64];   /* 16 KB */                      \
    const int tid = threadIdx.x;                                               \
    const int lane = tid & 63, wav = tid >> 6;                                 \
    const int r16 = lane & 15, quad = lane >> 4;                               \
    const int M0 = (M0_), N0 = (N0_);                                          \
    const int wm = wav >> 1, wn = wav & 1;                                     \
    const int m0 = M0 + wm * 128, n0 = N0 + wn * 64;                           \
    const int rr0 = tid >> 3;                                                  \
    const int cc0 = (tid - rr0) & 7;                                           \
    const unsigned short* pA0 = A_ + (size_t)(M0 + rr0) * Kc + cc0 * 8;        \
    const unsigned short* pB0 = B_ + (size_t)(N0 + rr0) * Kc + cc0 * 8;        \
    unsigned short* lA0 = As + (size_t)(wav * 64) * 8;                         \
    unsigned short* lB0 = Bs + (size_t)(wav * 64) * 8;                         \
    const int fa = wm * 128 + r16, fb = wn * 64 + r16;                         \
    const int swa0 = (quad + fa) & 7, swa1 = (swa0 + 4) & 7;                   \
    const int swb0 = (quad + fb) & 7, swb1 = (swb0 + 4) & 7;                   \
    floatx4 acc[8][4];                                                         \
    _Pragma("unroll") for (int i = 0; i < 8; i++)                              \
        _Pragma("unroll") for (int j = 0; j < 4; j++) acc[i][j] = (floatx4)0.0f; \
    _Pragma("unroll 1") for (int ks = 0; ks < (Kc / 64); ks++) {               \
        _Pragma("unroll") for (int p = 0; p < 8; p++)                          \
            GLL16(pA0 + (size_t)ks * 64 + (size_t)p * 32 * Kc,                 \
                  lA0 + (size_t)p * 2048);                                     \
        _Pragma("unroll") for (int p = 0; p < 4; p++)                          \
            GLL16(pB0 + (size_t)ks * 64 + (size_t)p * 32 * Kc,                 \
                  lB0 + (size_t)p * 2048);                                     \
        __syncthreads();                                                       \
        short8 af[8], bf[4];                                                   \
        _Pragma("unroll") for (int i = 0; i < 8; i++)                          \
            af[i] = *(const short8*)(As + (fa + i * 16) * 64 + swa0 * 8);      \
        _Pragma("unroll") for (int j = 0; j < 4; j++)                          \
            bf[j] = *(const short8*)(Bs + (fb + j * 16) * 64 + swb0 * 8);      \
        _Pragma("unroll") for (int i = 0; i < 8; i++)                          \
            _Pragma("unroll") for (int j = 0; j < 4; j++)                      \
                acc[i][j] = __builtin_amdgcn_mfma_f32_16x16x32_bf16(           \
                    af[i], bf[j], acc[i][j], 0, 0, 0);                         \
        _Pragma("unroll") for (int i = 0; i < 8; i++)                          \
            af[i] = *(const short8*)(As + (fa + i * 16) * 64 + swa1 * 8);      \
        _Pragma("unroll") for (int j = 0; j < 4; j++)                          \
            bf[j] = *(const short8*)(Bs + (fb + j * 16) * 64 + swb1 * 8);      \
        _Pragma("unroll") for (int i = 0; i < 8; i++)                          \
            _Pragma("unroll") for (int j = 0; j < 4; j++)                      \
                acc[i][j] = __builtin_amdgcn_mfma_f32_16x16x32_bf16(           \
                    af[i], bf[j], acc[i][j], 0, 0, 0);                         \
        __syncthreads();                                                       \
    }

// ---------------- GEMM1: qkv = xb @ Wab^T, fused norm+erf -> E --------------
// 1-D grid 768 (24 x-tiles x 32 y-tiles), XCD-bijective swizzle: XCD k owns
// y in [4k, 4k+4) -> its 4 A-panels (2MB) stay L2-resident across the x-sweep.
// E layout: [three][b][h][t][hs], bf16 bits.
__global__ __launch_bounds__(256, 2) void gemm1_qkv_norm(const unsigned short* __restrict__ A,
                                                         const unsigned short* __restrict__ Bm,
                                                         unsigned short* __restrict__ E) {
    const int wg = blockIdx.x;                 // 0..767
    const int swz = (wg & 7) * 96 + (wg >> 3); // bijective, 768 % 8 == 0
    const int bx = swz % 24, by = swz / 24;
    GEMM_CORE_BIG(A, Bm, 1024, by * 256, bx * 128)

    // fused per-64-group normalization: this wave's 64-col tile == one (three,h)
    int gcol  = n0 >> 6;            // 0..47
    int three = gcol >> 4, h = gcol & 15;
    #pragma unroll
    for (int i = 0; i < 8; i++) {
        #pragma unroll
        for (int r = 0; r < 4; r++) {
            float s = 0.f, ss = 0.f;
            #pragma unroll
            for (int j = 0; j < 4; j++) { float v = acc[i][j][r]; s += v; ss += v * v; }
            s = sum16(s); ss = sum16(ss);
            float mean = s * (1.0f / 64.0f);
            float var  = (ss - s * s * (1.0f / 64.0f)) * (1.0f / 63.0f);  // ddof=1
            float rstd = rsqrtf(var);
            int rowm = m0 + i * 16 + quad * 4 + r;     // = b*2048 + t
            int bb = rowm >> 11, tt2 = rowm & 2047;
            size_t base = ((((size_t)three * 4 + bb) * 16 + h) * 2048 + tt2) * 64;
            #pragma unroll
            for (int j = 0; j < 4; j++) {
                float v = (acc[i][j][r] - mean) * rstd;
                if (three < 2) v = erf_fast(v);
                E[base + j * 16 + r16] = f2bf(v);
            }
        }
    }
}

// ---------------- GEMM2: out = x + vt @ Wp^T (fp32 out) ---------------------
// 128x128 block tile, 4 waves 2x2, wave tile 64x64 (acc[4][4]). BK=64.
// 1-D grid 512 (8 x-tiles x 64 y-tiles), XCD swizzle: XCD k owns y in
// [8k, 8k+8) -> A-panels L2-resident; Wpb (2MB) L2-resident too.
__global__ __launch_bounds__(256, 2) void gemm2_proj_add(const unsigned short* __restrict__ A,
                                                         const unsigned short* __restrict__ Bm,
                                                         const float* __restrict__ X,
                                                         float* __restrict__ Out) {
    __shared__ unsigned short As[128 * 64];   // 16 KB
    __shared__ unsigned short Bs[128 * 64];   // 16 KB
    const int wg = blockIdx.x;                 // 0..511
    const int swz = (wg & 7) * 64 + (wg >> 3); // bijective, 512 % 8 == 0
    const int bx = swz & 7, by = swz >> 3;
    const int tid = threadIdx.x;
    const int lane = tid & 63, wav = tid >> 6;
    const int r16 = lane & 15, quad = lane >> 4;
    const int M0 = by * 128, N0 = bx * 128;
    const int wm = wav >> 1, wn = wav & 1;
    const int m0 = M0 + wm * 64, n0 = N0 + wn * 64;
    const int rr0 = tid >> 3;                      // 0..31
    const int cc0 = (tid - rr0) & 7;
    const unsigned short* pA0 = A  + (size_t)(M0 + rr0) * 1024 + cc0 * 8;
    const unsigned short* pB0 = Bm + (size_t)(N0 + rr0) * 1024 + cc0 * 8;
    unsigned short* lA0 = As + (size_t)(wav * 64) * 8;
    unsigned short* lB0 = Bs + (size_t)(wav * 64) * 8;
    const int fa = wm * 64 + r16, fb = wn * 64 + r16;
    const int swa0 = (quad + fa) & 7, swa1 = (swa0 + 4) & 7;
    const int swb0 = (quad + fb) & 7, swb1 = (swb0 + 4) & 7;
    floatx4 acc[4][4];
    #pragma unroll
    for (int i = 0; i < 4; i++)
        #pragma unroll
        for (int j = 0; j < 4; j++) acc[i][j] = (floatx4)0.0f;

    #pragma unroll 1
    for (int ks = 0; ks < 16; ks++) {
        #pragma unroll
        for (int p = 0; p < 4; p++)
            GLL16(pA0 + (size_t)ks * 64 + (size_t)p * 32 * 1024, lA0 + (size_t)p * 2048);
        #pragma unroll
        for (int p = 0; p < 4; p++)
            GLL16(pB0 + (size_t)ks * 64 + (size_t)p * 32 * 1024, lB0 + (size_t)p * 2048);
        __syncthreads();
        short8 af[4], bf[4];
        #pragma unroll
        for (int i = 0; i < 4; i++)
            af[i] = *(const short8*)(As + (fa + i * 16) * 64 + swa0 * 8);
        #pragma unroll
        for (int j = 0; j < 4; j++)
            bf[j] = *(const short8*)(Bs + (fb + j * 16) * 64 + swb0 * 8);
        #pragma unroll
        for (int i = 0; i < 4; i++)
            #pragma unroll
            for (int j = 0; j < 4; j++)
                acc[i][j] = __builtin_amdgcn_mfma_f32_16x16x32_bf16(
                    af[i], bf[j], acc[i][j], 0, 0, 0);
        #pragma unroll
        for (int i = 0; i < 4; i++)
            af[i] = *(const short8*)(As + (fa + i * 16) * 64 + swa1 * 8);
        #pragma unroll
        for (int j = 0; j < 4; j++)
            bf[j] = *(const short8*)(Bs + (fb + j * 16) * 64 + swb1 * 8);
        #pragma unroll
        for (int i = 0; i < 4; i++)
            #pragma unroll
            for (int j = 0; j < 4; j++)
                acc[i][j] = __builtin_amdgcn_mfma_f32_16x16x32_bf16(
                    af[i], bf[j], acc[i][j], 0, 0, 0);
        __syncthreads();
    }

    #pragma unroll
    for (int i = 0; i < 4; i++)
        #pragma unroll
        for (int j = 0; j < 4; j++)
            #pragma unroll
            for (int r = 0; r < 4; r++) {
                size_t idx = (size_t)(m0 + i * 16 + quad * 4 + r) * 1024 + (n0 + j * 16 + r16);
                Out[idx] = acc[i][j][r] + X[idx];
            }
}

// ---------------- rolling chunked scan -> vt --------------------------------
// Exact recursion carried in registers: sv_t = v_t - G_t * sv_{t-1},
//   G_t = k~_{t-1}.k_t ; vt_t[i] = H0 sv_t[i] + w_i H1 sv_{t-1}[i].
// One wave per (b,h,chunk-of-16): 64 x 128 = 8192 waves = 2048 blocks.
__global__ __launch_bounds__(256) void band_vt(const unsigned short* __restrict__ E,
                                               const float* __restrict__ w,
                                               const float* __restrict__ eta,
                                               unsigned short* __restrict__ vt) {
    const int lane = threadIdx.x & 63;
    const int wav  = threadIdx.x >> 6;
    const int gid  = blockIdx.x * 4 + wav;        // 0..8191
    const int chunk = gid & 127;                  // 128 chunks of 16 t
    const int p     = gid >> 7;                   // (b,h): 0..63
    const int b = p >> 4, h = p & 15;
    const int t0 = chunk * 16;

    const size_t PL = (size_t)4 * 16 * 2048 * 64;               // one "three" plane
    const size_t pbh = ((size_t)b * 16 + h) * (2048 * 64);
    const unsigned short* qb = E + pbh;
    const unsigned short* kb = E + PL + pbh;
    const unsigned short* vb = E + 2 * PL + pbh;

    const float e  = eta[h * 64 + lane];
    const float wi = w[h * 64 + lane];

    // ---- warm-up: rolling kh_{t0-1} and seeded sv_{t0-1} (wave-uniform guards)
    float kh_p, sv_p;
    if (t0 == 0) {
        kh_p = 0.f;
        sv_p = 0.f;
    } else {
        float k1 = bflo(kb[(size_t)(t0 - 1) * 64 + lane]);
        float k2 = bflo(kb[(size_t)(t0 - 2) * 64 + lane]);
        float k3 = bflo(kb[(size_t)(t0 - 3) * 64 + lane]);
        float v1 = bflo(vb[(size_t)(t0 - 1) * 64 + lane]);
        float v2 = bflo(vb[(size_t)(t0 - 2) * 64 + lane]);
        float v3 = bflo(vb[(size_t)(t0 - 3) * 64 + lane]);
        float G1 = sum64_all((k2 * e) * k1);      // G_{t0-1} = k~_{t0-2}.k_{t0-1}
        float G2 = sum64_all((k3 * e) * k2);      // G_{t0-2} = k~_{t0-3}.k_{t0-2}
        sv_p = v1 - G1 * (v2 - G2 * v3);          // sv_{t0-1}, 3-term seed
        kh_p = k1 * e;
    }

    const unsigned short* pq = qb + (size_t)t0 * 64 + lane;
    const unsigned short* pk = kb + (size_t)t0 * 64 + lane;
    const unsigned short* pv = vb + (size_t)t0 * 64 + lane;
    unsigned short* po = vt + ((size_t)b * 2048 + t0) * 1024 + h * 64 + lane;

    #pragma unroll
    for (int tt = 0; tt < 16; tt++) {
        float qt = bflo(pq[tt * 64]);
        float kt = bflo(pk[tt * 64]);
        float vv = bflo(pv[tt * 64]);
        float kh = kt * e;
        float Gt = sum64_all(kh_p * kt);          // k~_{t-1}.k_t
        float H0 = sum64_all(kh * qt);            // k~_t.q_t
        float H1 = sum64_all(kh_p * qt);          // k~_{t-1}.q_t
        float sv = fmaf(-Gt, sv_p, vv);           // sv_t = v_t - G_t sv_{t-1}
        float r  = fmaf(H0, sv, wi * (H1 * sv_p));
        po[(size_t)tt * 1024] = f2bf(r);
        kh_p = kh;
        sv_p = sv;
    }
}

// ---------------------------------------------------------------------------
extern "C" void kernel_launch(void* const* d_in, const int* in_sizes, int n_in,
                              void* d_out, int out_size, void* d_ws, size_t ws_size,
                              hipStream_t stream) {
    const float* x   = (const float*)d_in[0];   // (4,2048,1024)
    const float* Wa  = (const float*)d_in[1];   // (3072,1024)
    const float* Wp  = (const float*)d_in[2];   // (1024,1024)
    const float* w   = (const float*)d_in[3];   // (1024,)
    const float* eta = (const float*)d_in[4];   // (1024,)
    float* out = (float*)d_out;

    char* ws = (char*)d_ws;
    unsigned short* xb  = (unsigned short*)(ws + 0);          // 16777216 B
    unsigned short* Wab = (unsigned short*)(ws + 16777216);   //  6291456 B
    unsigned short* Wpb = (unsigned short*)(ws + 23068672);   //  2097152 B
    unsigned short* E   = (unsigned short*)(ws + 25165824);   // 50331648 B
    unsigned short* vtb = (unsigned short*)(ws + 75497728);   // 16777216 B  -> end 92274944

    castall<<<3072, 256, 0, stream>>>((const float4*)x, (const float4*)Wa,
                                      (const float4*)Wp, (uint2*)xb);

    gemm1_qkv_norm<<<768, 256, 0, stream>>>(xb, Wab, E);
    band_vt<<<2048, 256, 0, stream>>>(E, w, eta, vtb);
    gemm2_proj_add<<<512, 256, 0, stream>>>(vtb, Wpb, x, out);
}

// Round 7
// 197.000 us; speedup vs baseline: 1.3011x; 1.0026x over previous
//
#include <hip/hip_runtime.h>
#include <math.h>

// ---------------------------------------------------------------------------
// RWKV7-ish CausalSelfAttention, MI355X gfx950.
// B=4 T=2048 C=1024 NH=16 HS=64.
// Pipeline: castall v2 (ILP-4) -> bf16 ;
//   GEMM1(256x128 block, BK=64, GLL16 + swizzled LDS, XCD swizzle,
//         3 blocks/CU) + fused groupnorm/fast-erf -> E ;
//   band_vt rolling chunked scan -> vt ;
//   GEMM2(128x128 block, BK=128 double-stage = half the barriers,
//         64KB LDS, 2 blocks/CU, XCD swizzle) + residual.
// R6 lesson: XCD swizzle fixed gemm1 FETCH (71->49.6MB) but not time ->
//   gemm1 is drain/stall-bound, not HBM-bound. R7: occupancy 2->3 blocks/CU
//   (the only lever that has won here) overlaps the vmcnt(0) drain; gemm2
//   halves barrier count via BK=128 two-half staging. Numerics unchanged.
// Workspace: xb 16MB | Wab 6MB | Wpb 2MB | E 48MB | vt 16MB = 88MiB
// ---------------------------------------------------------------------------

typedef __attribute__((ext_vector_type(8))) short short8;     // 8 x bf16 bits
typedef __attribute__((ext_vector_type(4))) float floatx4;

#define GLL16(g, l)                                                            \
    __builtin_amdgcn_global_load_lds(                                          \
        (const __attribute__((address_space(1))) void*)(g),                    \
        (__attribute__((address_space(3))) void*)(l), 16, 0, 0)

static __device__ __forceinline__ unsigned short f2bf(float f) {
    unsigned u = __float_as_uint(f);
    unsigned r = (u + 0x7fffu + ((u >> 16) & 1u)) >> 16;
    return (unsigned short)r;
}
static __device__ __forceinline__ float bflo(unsigned v) { return __uint_as_float(v << 16); }

// Abramowitz-Stegun 7.1.28: |err| <= 3e-7, branch-free.
static __device__ __forceinline__ float erf_fast(float x) {
    float ax = __builtin_fabsf(x);
    float p = fmaf(0.0000430638f, ax, 0.0002765672f);
    p = fmaf(p, ax, 0.0001520143f);
    p = fmaf(p, ax, 0.0092705272f);
    p = fmaf(p, ax, 0.0422820123f);
    p = fmaf(p, ax, 0.0705230784f);
    p = fmaf(p, ax, 1.0f);
    float r = 1.0f / p;
    float r2 = r * r, r4 = r2 * r2, r8 = r4 * r4, r16 = r8 * r8;
    return __builtin_copysignf(1.0f - r16, x);
}

// sum across the 16 lanes of a DPP row, result in every lane of the row.
static __device__ __forceinline__ float sum16(float x) {
    int t;
    t = __builtin_amdgcn_update_dpp(0, __float_as_int(x), 0x128, 0xf, 0xf, false); // row_ror:8
    x += __int_as_float(t);
    t = __builtin_amdgcn_update_dpp(0, __float_as_int(x), 0x124, 0xf, 0xf, false); // row_ror:4
    x += __int_as_float(t);
    t = __builtin_amdgcn_update_dpp(0, __float_as_int(x), 0x122, 0xf, 0xf, false); // row_ror:2
    x += __int_as_float(t);
    t = __builtin_amdgcn_update_dpp(0, __float_as_int(x), 0x121, 0xf, 0xf, false); // row_ror:1
    x += __int_as_float(t);
    return x;
}
// full 64-lane sum, result in every lane.
static __device__ __forceinline__ float sum64_all(float x) {
    x = sum16(x);
    int t = __builtin_amdgcn_ds_swizzle(__float_as_int(x), 0x401F);  // xor 16 (within 32)
    x += __int_as_float(t);
    x += __shfl_xor(x, 32, 64);                                      // xor 32
    return x;
}

// ---------------- fused cast fp32 -> bf16 (x | Wa | Wp, contiguous out) -----
__global__ __launch_bounds__(256) void castall(const float4* __restrict__ x,
                                               const float4* __restrict__ wa,
                                               const float4* __restrict__ wp,
                                               uint2* __restrict__ out) {
    int base = blockIdx.x * 1024 + threadIdx.x;
    #pragma unroll
    for (int k = 0; k < 4; k++) {
        int i = base + k * 256;
        const float4* src;
        int off;
        if (i < 2097152)      { src = x;  off = 0; }
        else if (i < 2883584) { src = wa; off = 2097152; }
        else                  { src = wp; off = 2883584; }
        float4 v = src[i - off];
        uint2 o;
        o.x = (unsigned)f2bf(v.x) | ((unsigned)f2bf(v.y) << 16);
        o.y = (unsigned)f2bf(v.z) | ((unsigned)f2bf(v.w) << 16);
        out[i] = o;
    }
}

// ---------------------------------------------------------------------------
// GEMM core (proven), C = A @ B^T. Block 256x128, 4 waves 2x2, wave tile
// 128x64 (acc[8][4]), BK=64, GLL16 staging, swizzled LDS (0 conflicts).
// ---------------------------------------------------------------------------
#define GEMM_CORE_BIG(A_, B_, Kc, M0_, N0_)                                    \
    __shared__ unsigned short As[256 * 64];   /* 32 KB */                      \
    __shared__ unsigned short Bs[128 * 64];   /* 16 KB */                      \
    const int tid = threadIdx.x;                                               \
    const int lane = tid & 63, wav = tid >> 6;                                 \
    const int r16 = lane & 15, quad = lane >> 4;                               \
    const int M0 = (M0_), N0 = (N0_);                                          \
    const int wm = wav >> 1, wn = wav & 1;                                     \
    const int m0 = M0 + wm * 128, n0 = N0 + wn * 64;                           \
    const int rr0 = tid >> 3;                                                  \
    const int cc0 = (tid - rr0) & 7;                                           \
    const unsigned short* pA0 = A_ + (size_t)(M0 + rr0) * Kc + cc0 * 8;        \
    const unsigned short* pB0 = B_ + (size_t)(N0 + rr0) * Kc + cc0 * 8;        \
    unsigned short* lA0 = As + (size_t)(wav * 64) * 8;                         \
    unsigned short* lB0 = Bs + (size_t)(wav * 64) * 8;                         \
    const int fa = wm * 128 + r16, fb = wn * 64 + r16;                         \
    const int swa0 = (quad + fa) & 7, swa1 = (swa0 + 4) & 7;                   \
    const int swb0 = (quad + fb) & 7, swb1 = (swb0 + 4) & 7;                   \
    floatx4 acc[8][4];                                                         \
    _Pragma("unroll") for (int i = 0; i < 8; i++)                              \
        _Pragma("unroll") for (int j = 0; j < 4; j++) acc[i][j] = (floatx4)0.0f; \
    _Pragma("unroll 1") for (int ks = 0; ks < (Kc / 64); ks++) {               \
        _Pragma("unroll") for (int p = 0; p < 8; p++)                          \
            GLL16(pA0 + (size_t)ks * 64 + (size_t)p * 32 * Kc,                 \
                  lA0 + (size_t)p * 2048);                                     \
        _Pragma("unroll") for (int p = 0; p < 4; p++)                          \
            GLL16(pB0 + (size_t)ks * 64 + (size_t)p * 32 * Kc,                 \
                  lB0 + (size_t)p * 2048);                                     \
        __syncthreads();                                                       \
        short8 af[8], bf[4];                                                   \
        _Pragma("unroll") for (int i = 0; i < 8; i++)                          \
            af[i] = *(const short8*)(As + (fa + i * 16) * 64 + swa0 * 8);      \
        _Pragma("unroll") for (int j = 0; j < 4; j++)                          \
            bf[j] = *(const short8*)(Bs + (fb + j * 16) * 64 + swb0 * 8);      \
        _Pragma("unroll") for (int i = 0; i < 8; i++)                          \
            _Pragma("unroll") for (int j = 0; j < 4; j++)                      \
                acc[i][j] = __builtin_amdgcn_mfma_f32_16x16x32_bf16(           \
                    af[i], bf[j], acc[i][j], 0, 0, 0);                         \
        _Pragma("unroll") for (int i = 0; i < 8; i++)                          \
            af[i] = *(const short8*)(As + (fa + i * 16) * 64 + swa1 * 8);      \
        _Pragma("unroll") for (int j = 0; j < 4; j++)                          \
            bf[j] = *(const short8*)(Bs + (fb + j * 16) * 64 + swb1 * 8);      \
        _Pragma("unroll") for (int i = 0; i < 8; i++)                          \
            _Pragma("unroll") for (int j = 0; j < 4; j++)                      \
                acc[i][j] = __builtin_amdgcn_mfma_f32_16x16x32_bf16(           \
                    af[i], bf[j], acc[i][j], 0, 0, 0);                         \
        __syncthreads();                                                       \
    }

// ---------------- GEMM1: qkv = xb @ Wab^T, fused norm+erf -> E --------------
// 1-D grid 768, XCD-bijective swizzle; 3 blocks/CU (144KB LDS, VGPR 84).
// E layout: [three][b][h][t][hs], bf16 bits.
__global__ __launch_bounds__(256, 3) void gemm1_qkv_norm(const unsigned short* __restrict__ A,
                                                         const unsigned short* __restrict__ Bm,
                                                         unsigned short* __restrict__ E) {
    const int wg = blockIdx.x;                 // 0..767
    const int swz = (wg & 7) * 96 + (wg >> 3); // bijective, 768 % 8 == 0
    const int bx = swz % 24, by = swz / 24;
    GEMM_CORE_BIG(A, Bm, 1024, by * 256, bx * 128)

    // fused per-64-group normalization: this wave's 64-col tile == one (three,h)
    int gcol  = n0 >> 6;            // 0..47
    int three = gcol >> 4, h = gcol & 15;
    #pragma unroll
    for (int i = 0; i < 8; i++) {
        #pragma unroll
        for (int r = 0; r < 4; r++) {
            float s = 0.f, ss = 0.f;
            #pragma unroll
            for (int j = 0; j < 4; j++) { float v = acc[i][j][r]; s += v; ss += v * v; }
            s = sum16(s); ss = sum16(ss);
            float mean = s * (1.0f / 64.0f);
            float var  = (ss - s * s * (1.0f / 64.0f)) * (1.0f / 63.0f);  // ddof=1
            float rstd = rsqrtf(var);
            int rowm = m0 + i * 16 + quad * 4 + r;     // = b*2048 + t
            int bb = rowm >> 11, tt2 = rowm & 2047;
            size_t base = ((((size_t)three * 4 + bb) * 16 + h) * 2048 + tt2) * 64;
            #pragma unroll
            for (int j = 0; j < 4; j++) {
                float v = (acc[i][j][r] - mean) * rstd;
                if (three < 2) v = erf_fast(v);
                E[base + j * 16 + r16] = f2bf(v);
            }
        }
    }
}

// ---------------- GEMM2: out = x + vt @ Wp^T (fp32 out) ---------------------
// 128x128 block tile, 4 waves 2x2, wave tile 64x64 (acc[4][4]).
// BK=128 double-stage: both 64-K halves staged into separate 32KB LDS halves
// per barrier pair -> 8 barrier pairs instead of 16. 64KB LDS, 2 blocks/CU.
// 1-D grid 512, XCD swizzle. K order identical -> bit-identical numerics.
__global__ __launch_bounds__(256, 2) void gemm2_proj_add(const unsigned short* __restrict__ A,
                                                         const unsigned short* __restrict__ Bm,
                                                         const float* __restrict__ X,
                                                         float* __restrict__ Out) {
    __shared__ unsigned short As[2 * 128 * 64];   // 32 KB
    __shared__ unsigned short Bs[2 * 128 * 64];   // 32 KB
    const int wg = blockIdx.x;                 // 0..511
    const int swz = (wg & 7) * 64 + (wg >> 3); // bijective, 512 % 8 == 0
    const int bx = swz & 7, by = swz >> 3;
    const int tid = threadIdx.x;
    const int lane = tid & 63, wav = tid >> 6;
    const int r16 = lane & 15, quad = lane >> 4;
    const int M0 = by * 128, N0 = bx * 128;
    const int wm = wav >> 1, wn = wav & 1;
    const int m0 = M0 + wm * 64, n0 = N0 + wn * 64;
    const int rr0 = tid >> 3;                      // 0..31
    const int cc0 = (tid - rr0) & 7;
    const unsigned short* pA0 = A  + (size_t)(M0 + rr0) * 1024 + cc0 * 8;
    const unsigned short* pB0 = Bm + (size_t)(N0 + rr0) * 1024 + cc0 * 8;
    unsigned short* lA0 = As + (size_t)(wav * 64) * 8;
    unsigned short* lB0 = Bs + (size_t)(wav * 64) * 8;
    const int fa = wm * 64 + r16, fb = wn * 64 + r16;
    const int swa0 = (quad + fa) & 7, swa1 = (swa0 + 4) & 7;
    const int swb0 = (quad + fb) & 7, swb1 = (swb0 + 4) & 7;
    floatx4 acc[4][4];
    #pragma unroll
    for (int i = 0; i < 4; i++)
        #pragma unroll
        for (int j = 0; j < 4; j++) acc[i][j] = (floatx4)0.0f;

    #pragma unroll 1
    for (int ks = 0; ks < 8; ks++) {               // 8 x BK=128 supersteps
        #pragma unroll
        for (int kh = 0; kh < 2; kh++) {           // two 64-K halves
            #pragma unroll
            for (int p = 0; p < 4; p++)
                GLL16(pA0 + (size_t)ks * 128 + kh * 64 + (size_t)p * 32 * 1024,
                      lA0 + kh * 8192 + (size_t)p * 2048);
            #pragma unroll
            for (int p = 0; p < 4; p++)
                GLL16(pB0 + (size_t)ks * 128 + kh * 64 + (size_t)p * 32 * 1024,
                      lB0 + kh * 8192 + (size_t)p * 2048);
        }
        __syncthreads();
        #pragma unroll
        for (int kh = 0; kh < 2; kh++) {
            const unsigned short* Ah = As + kh * 8192;
            const unsigned short* Bh = Bs + kh * 8192;
            short8 af[4], bf[4];
            #pragma unroll
            for (int i = 0; i < 4; i++)
                af[i] = *(const short8*)(Ah + (fa + i * 16) * 64 + swa0 * 8);
            #pragma unroll
            for (int j = 0; j < 4; j++)
                bf[j] = *(const short8*)(Bh + (fb + j * 16) * 64 + swb0 * 8);
            #pragma unroll
            for (int i = 0; i < 4; i++)
                #pragma unroll
                for (int j = 0; j < 4; j++)
                    acc[i][j] = __builtin_amdgcn_mfma_f32_16x16x32_bf16(
                        af[i], bf[j], acc[i][j], 0, 0, 0);
            #pragma unroll
            for (int i = 0; i < 4; i++)
                af[i] = *(const short8*)(Ah + (fa + i * 16) * 64 + swa1 * 8);
            #pragma unroll
            for (int j = 0; j < 4; j++)
                bf[j] = *(const short8*)(Bh + (fb + j * 16) * 64 + swb1 * 8);
            #pragma unroll
            for (int i = 0; i < 4; i++)
                #pragma unroll
                for (int j = 0; j < 4; j++)
                    acc[i][j] = __builtin_amdgcn_mfma_f32_16x16x32_bf16(
                        af[i], bf[j], acc[i][j], 0, 0, 0);
        }
        __syncthreads();
    }

    #pragma unroll
    for (int i = 0; i < 4; i++)
        #pragma unroll
        for (int j = 0; j < 4; j++)
            #pragma unroll
            for (int r = 0; r < 4; r++) {
                size_t idx = (size_t)(m0 + i * 16 + quad * 4 + r) * 1024 + (n0 + j * 16 + r16);
                Out[idx] = acc[i][j][r] + X[idx];
            }
}

// ---------------- rolling chunked scan -> vt --------------------------------
// Exact recursion carried in registers: sv_t = v_t - G_t * sv_{t-1},
//   G_t = k~_{t-1}.k_t ; vt_t[i] = H0 sv_t[i] + w_i H1 sv_{t-1}[i].
// One wave per (b,h,chunk-of-16): 64 x 128 = 8192 waves = 2048 blocks.
__global__ __launch_bounds__(256) void band_vt(const unsigned short* __restrict__ E,
                                               const float* __restrict__ w,
                                               const float* __restrict__ eta,
                                               unsigned short* __restrict__ vt) {
    const int lane = threadIdx.x & 63;
    const int wav  = threadIdx.x >> 6;
    const int gid  = blockIdx.x * 4 + wav;        // 0..8191
    const int chunk = gid & 127;                  // 128 chunks of 16 t
    const int p     = gid >> 7;                   // (b,h): 0..63
    const int b = p >> 4, h = p & 15;
    const int t0 = chunk * 16;

    const size_t PL = (size_t)4 * 16 * 2048 * 64;               // one "three" plane
    const size_t pbh = ((size_t)b * 16 + h) * (2048 * 64);
    const unsigned short* qb = E + pbh;
    const unsigned short* kb = E + PL + pbh;
    const unsigned short* vb = E + 2 * PL + pbh;

    const float e  = eta[h * 64 + lane];
    const float wi = w[h * 64 + lane];

    // ---- warm-up: rolling kh_{t0-1} and seeded sv_{t0-1} (wave-uniform guards)
    float kh_p, sv_p;
    if (t0 == 0) {
        kh_p = 0.f;
        sv_p = 0.f;
    } else {
        float k1 = bflo(kb[(size_t)(t0 - 1) * 64 + lane]);
        float k2 = bflo(kb[(size_t)(t0 - 2) * 64 + lane]);
        float k3 = bflo(kb[(size_t)(t0 - 3) * 64 + lane]);
        float v1 = bflo(vb[(size_t)(t0 - 1) * 64 + lane]);
        float v2 = bflo(vb[(size_t)(t0 - 2) * 64 + lane]);
        float v3 = bflo(vb[(size_t)(t0 - 3) * 64 + lane]);
        float G1 = sum64_all((k2 * e) * k1);      // G_{t0-1} = k~_{t0-2}.k_{t0-1}
        float G2 = sum64_all((k3 * e) * k2);      // G_{t0-2} = k~_{t0-3}.k_{t0-2}
        sv_p = v1 - G1 * (v2 - G2 * v3);          // sv_{t0-1}, 3-term seed
        kh_p = k1 * e;
    }

    const unsigned short* pq = qb + (size_t)t0 * 64 + lane;
    const unsigned short* pk = kb + (size_t)t0 * 64 + lane;
    const unsigned short* pv = vb + (size_t)t0 * 64 + lane;
    unsigned short* po = vt + ((size_t)b * 2048 + t0) * 1024 + h * 64 + lane;

    #pragma unroll
    for (int tt = 0; tt < 16; tt++) {
        float qt = bflo(pq[tt * 64]);
        float kt = bflo(pk[tt * 64]);
        float vv = bflo(pv[tt * 64]);
        float kh = kt * e;
        float Gt = sum64_all(kh_p * kt);          // k~_{t-1}.k_t
        float H0 = sum64_all(kh * qt);            // k~_t.q_t
        float H1 = sum64_all(kh_p * qt);          // k~_{t-1}.q_t
        float sv = fmaf(-Gt, sv_p, vv);           // sv_t = v_t - G_t sv_{t-1}
        float r  = fmaf(H0, sv, wi * (H1 * sv_p));
        po[(size_t)tt * 1024] = f2bf(r);
        kh_p = kh;
        sv_p = sv;
    }
}

// ---------------------------------------------------------------------------
extern "C" void kernel_launch(void* const* d_in, const int* in_sizes, int n_in,
                              void* d_out, int out_size, void* d_ws, size_t ws_size,
                              hipStream_t stream) {
    const float* x   = (const float*)d_in[0];   // (4,2048,1024)
    const float* Wa  = (const float*)d_in[1];   // (3072,1024)
    const float* Wp  = (const float*)d_in[2];   // (1024,1024)
    const float* w   = (const float*)d_in[3];   // (1024,)
    const float* eta = (const float*)d_in[4];   // (1024,)
    float* out = (float*)d_out;

    char* ws = (char*)d_ws;
    unsigned short* xb  = (unsigned short*)(ws + 0);          // 16777216 B
    unsigned short* Wab = (unsigned short*)(ws + 16777216);   //  6291456 B
    unsigned short* Wpb = (unsigned short*)(ws + 23068672);   //  2097152 B
    unsigned short* E   = (unsigned short*)(ws + 25165824);   // 50331648 B
    unsigned short* vtb = (unsigned short*)(ws + 75497728);   // 16777216 B  -> end 92274944

    castall<<<3072, 256, 0, stream>>>((const float4*)x, (const float4*)Wa,
                                      (const float4*)Wp, (uint2*)xb);

    gemm1_qkv_norm<<<768, 256, 0, stream>>>(xb, Wab, E);
    band_vt<<<2048, 256, 0, stream>>>(E, w, eta, vtb);
    gemm2_proj_add<<<512, 256, 0, stream>>>(vtb, Wpb, x, out);
}